// Round 1
// baseline (2689.057 us; speedup 1.0000x reference)
//
#include <hip/hip_runtime.h>
#include <math.h>

#define B_ 4
#define C_ 128
#define CI_ 64
#define H_ 96
#define W_ 96
#define HW_ (H_*W_)      // 9216
#define NP_ 2304         // 48*48
#define GROUPS_ 32
#define EPS_ 1e-5f

// ---------------------------------------------------------------------------
// Kernel 1: fused 3-way 1x1 conv projections.
// out[b][n][ci] = bias[ci] + sum_c w[ci][c] * x[b][c][n]
// Tile: 32 pixels x 64 ci per block (256 threads, 8 outputs/thread).
// ---------------------------------------------------------------------------
__global__ __launch_bounds__(256) void proj_kernel(
    const float* __restrict__ x,
    const float* __restrict__ w_theta, const float* __restrict__ b_theta,
    const float* __restrict__ w_phi,   const float* __restrict__ b_phi,
    const float* __restrict__ w_g,     const float* __restrict__ b_g,
    float* __restrict__ Qo, float* __restrict__ phiF, float* __restrict__ gF)
{
    __shared__ float xs[C_ * 32];   // xs[c*32 + pix]           16 KB
    __shared__ float ws[C_ * 68];   // ws[c*68 + ci], pad->68   34.8 KB (16B-aligned rows)
    const int t    = threadIdx.x;
    const int tile = blockIdx.x;    // 288 tiles of 32 pixels
    const int b    = blockIdx.y;
    const int mat  = blockIdx.z;    // 0=theta, 1=phi, 2=g
    const float* wsel = (mat == 0) ? w_theta : (mat == 1) ? w_phi : w_g;
    const float* bsel = (mat == 0) ? b_theta : (mat == 1) ? b_phi : b_g;
    float* osel       = (mat == 0) ? Qo      : (mat == 1) ? phiF  : gF;
    const int n0 = tile * 32;

    // stage x tile [128][32] (coalesced: lane over pixel)
    {
        const int pix = t & 31;
        const int c0  = t >> 5;     // 0..7
        const float* xb = x + (size_t)b * C_ * HW_ + n0 + pix;
        for (int c = c0; c < C_; c += 8)
            xs[c * 32 + pix] = xb[(size_t)c * HW_];
    }
    // stage w transposed: ws[c][ci]
    for (int j = t; j < CI_ * C_; j += 256)          // 8192
        ws[(j & 127) * 68 + (j >> 7)] = wsel[j];
    __syncthreads();

    const int tp = (t & 7) * 4;     // 4 pixels
    const int tc = (t >> 3) * 2;    // 2 ci
    float acc[4][2] = {};
    #pragma unroll 4
    for (int c = 0; c < C_; ++c) {
        const float4 xv = *(const float4*)&xs[c * 32 + tp];
        const float2 wv = *(const float2*)&ws[c * 68 + tc];
        const float xa[4] = {xv.x, xv.y, xv.z, xv.w};
        #pragma unroll
        for (int i = 0; i < 4; ++i) {
            acc[i][0] += xa[i] * wv.x;
            acc[i][1] += xa[i] * wv.y;
        }
    }
    const float2 bb = *(const float2*)&bsel[tc];
    #pragma unroll
    for (int i = 0; i < 4; ++i) {
        float2 v = { acc[i][0] + bb.x, acc[i][1] + bb.y };
        *(float2*)&osel[((size_t)b * HW_ + n0 + tp + i) * CI_ + tc] = v;
    }
}

// ---------------------------------------------------------------------------
// Kernel 2: 2x2 maxpool  phiF/gF [b][n][ci] -> K/V [b][m][ci], m over 48x48
// ---------------------------------------------------------------------------
__global__ __launch_bounds__(256) void pool_kernel(
    const float* __restrict__ phiF, const float* __restrict__ gF,
    float* __restrict__ Ko, float* __restrict__ Vo)
{
    const int t   = threadIdx.x;
    const int b   = blockIdx.y;
    const int mat = blockIdx.z;                 // 0 -> K, 1 -> V
    const int idx = blockIdx.x * 256 + t;       // 0..147455
    const int m   = idx >> 6;
    const int ci  = idx & 63;
    const int ph  = m / 48, pw = m % 48;
    const int n00 = (ph * 2) * W_ + pw * 2;
    const float* src = mat ? gF : phiF;
    float* dst       = mat ? Vo : Ko;
    const float* p = src + ((size_t)b * HW_ + n00) * CI_ + ci;
    float v = fmaxf(fmaxf(p[0], p[CI_]),
                    fmaxf(p[(size_t)W_ * CI_], p[(size_t)(W_ + 1) * CI_]));
    dst[((size_t)b * NP_ + m) * CI_ + ci] = v;
}

// ---------------------------------------------------------------------------
// Kernel 3: flash-style attention (fp32 vector baseline).
// One thread = one Q row; block = 1 wave = 64 rows. K/V tiles (16x64) in LDS.
// ---------------------------------------------------------------------------
__global__ __launch_bounds__(64) void attn_kernel(
    const float* __restrict__ Qg, const float* __restrict__ Kg,
    const float* __restrict__ Vg, float* __restrict__ Yg)
{
    __shared__ float Ks[16 * 64];
    __shared__ float Vs[16 * 64];
    const int t = threadIdx.x;
    const int b = blockIdx.y;
    const size_t n = (size_t)blockIdx.x * 64 + t;

    const float* qp = Qg + ((size_t)b * HW_ + n) * CI_;
    float q[64], o[64];
    #pragma unroll
    for (int i = 0; i < 16; ++i) {
        float4 v = *(const float4*)(qp + 4 * i);
        q[4*i] = v.x; q[4*i+1] = v.y; q[4*i+2] = v.z; q[4*i+3] = v.w;
    }
    #pragma unroll
    for (int i = 0; i < 64; ++i) o[i] = 0.f;
    float mrun = -1e30f, lrun = 0.f;

    for (int kt = 0; kt < NP_ / 16; ++kt) {      // 144 tiles
        __syncthreads();
        const float* kbase = Kg + ((size_t)b * NP_ + kt * 16) * CI_;
        const float* vbase = Vg + ((size_t)b * NP_ + kt * 16) * CI_;
        #pragma unroll
        for (int i = 0; i < 16; ++i) {
            const int j = i * 64 + t;
            Ks[j] = kbase[j];
            Vs[j] = vbase[j];
        }
        __syncthreads();

        float s[16];
        float tmax = -1e30f;
        #pragma unroll
        for (int k = 0; k < 16; ++k) {
            float acc = 0.f;
            #pragma unroll
            for (int ic = 0; ic < 16; ++ic) {
                const float4 kv = *(const float4*)&Ks[k * 64 + 4 * ic];
                acc += q[4*ic]   * kv.x;
                acc += q[4*ic+1] * kv.y;
                acc += q[4*ic+2] * kv.z;
                acc += q[4*ic+3] * kv.w;
            }
            s[k] = acc;
            tmax = fmaxf(tmax, acc);
        }
        const float mnew  = fmaxf(mrun, tmax);
        const float scale = __expf(mrun - mnew);
        lrun *= scale;
        #pragma unroll
        for (int i = 0; i < 64; ++i) o[i] *= scale;
        #pragma unroll
        for (int k = 0; k < 16; ++k) {
            const float p = __expf(s[k] - mnew);
            lrun += p;
            #pragma unroll
            for (int ic = 0; ic < 16; ++ic) {
                const float4 vv = *(const float4*)&Vs[k * 64 + 4 * ic];
                o[4*ic]   += p * vv.x;
                o[4*ic+1] += p * vv.y;
                o[4*ic+2] += p * vv.z;
                o[4*ic+3] += p * vv.w;
            }
        }
        mrun = mnew;
    }

    const float inv = 1.0f / lrun;
    float* yp = Yg + ((size_t)b * HW_ + n) * CI_;
    #pragma unroll
    for (int i = 0; i < 16; ++i) {
        float4 v = { o[4*i] * inv, o[4*i+1] * inv, o[4*i+2] * inv, o[4*i+3] * inv };
        *(float4*)(yp + 4 * i) = v;
    }
}

// ---------------------------------------------------------------------------
// Kernel 4: 1x1 conv back to 128 channels. Z[b][o][n] = bW[o] + sum_ci wW[o][ci]*Y[b][n][ci]
// Tile: 64 pixels x 128 outputs per block.
// ---------------------------------------------------------------------------
__global__ __launch_bounds__(256) void conv2_kernel(
    const float* __restrict__ Yg, const float* __restrict__ wW,
    const float* __restrict__ bW, float* __restrict__ Zg)
{
    __shared__ float ys[CI_ * 68];    // ys[ci*68 + pix]     17.4 KB
    __shared__ float ws2[CI_ * 132];  // ws2[ci*132 + o]     33.8 KB
    const int t  = threadIdx.x;
    const int b  = blockIdx.y;
    const int n0 = blockIdx.x * 64;

    const float* ybase = Yg + ((size_t)b * HW_ + n0) * CI_;
    for (int j = t; j < 64 * CI_; j += 256)      // 4096: pix=j>>6, ci=j&63
        ys[(j & 63) * 68 + (j >> 6)] = ybase[j];
    for (int j = t; j < C_ * CI_; j += 256)      // 8192: o=j>>6, ci=j&63
        ws2[(j & 63) * 132 + (j >> 6)] = wW[j];
    __syncthreads();

    const int tp = (t & 15) * 4;   // 4 pixels
    const int to = (t >> 4) * 8;   // 8 outputs
    float acc[4][8] = {};
    #pragma unroll 2
    for (int ci = 0; ci < CI_; ++ci) {
        const float4 yv  = *(const float4*)&ys[ci * 68 + tp];
        const float4 wv0 = *(const float4*)&ws2[ci * 132 + to];
        const float4 wv1 = *(const float4*)&ws2[ci * 132 + to + 4];
        const float ya[4] = {yv.x, yv.y, yv.z, yv.w};
        const float wa[8] = {wv0.x, wv0.y, wv0.z, wv0.w, wv1.x, wv1.y, wv1.z, wv1.w};
        #pragma unroll
        for (int i = 0; i < 4; ++i)
            #pragma unroll
            for (int j = 0; j < 8; ++j)
                acc[i][j] += ya[i] * wa[j];
    }
    #pragma unroll
    for (int j = 0; j < 8; ++j) {
        const int o = to + j;
        const float bb = bW[o];
        float* zp = Zg + ((size_t)b * C_ + o) * HW_ + n0 + tp;
        float4 v = { acc[0][j] + bb, acc[1][j] + bb, acc[2][j] + bb, acc[3][j] + bb };
        *(float4*)zp = v;
    }
}

// ---------------------------------------------------------------------------
// Kernel 5: GroupNorm stats (mean, rstd) per (b, group). Deterministic (no atomics).
// ---------------------------------------------------------------------------
__global__ __launch_bounds__(256) void stats_kernel(
    const float* __restrict__ Zg, float* __restrict__ stats)
{
    const int t  = threadIdx.x;
    const int gr = blockIdx.x;   // 0..31
    const int b  = blockIdx.y;
    const float4* zp = (const float4*)(Zg + ((size_t)b * C_ + gr * 4) * HW_);
    float s = 0.f, ss = 0.f;
    for (int i = t; i < HW_; i += 256) {          // 9216 float4 = 4 channels * HW
        const float4 v = zp[i];
        s  += v.x + v.y + v.z + v.w;
        ss += v.x*v.x + v.y*v.y + v.z*v.z + v.w*v.w;
    }
    __shared__ float rs[256], rq[256];
    rs[t] = s; rq[t] = ss;
    __syncthreads();
    for (int off = 128; off > 0; off >>= 1) {
        if (t < off) { rs[t] += rs[t + off]; rq[t] += rq[t + off]; }
        __syncthreads();
    }
    if (t == 0) {
        const float invn = 1.0f / (4 * HW_);
        const float mean = rs[0] * invn;
        const float var  = rq[0] * invn - mean * mean;
        stats[((size_t)b * GROUPS_ + gr) * 2 + 0] = mean;
        stats[((size_t)b * GROUPS_ + gr) * 2 + 1] = rsqrtf(var + EPS_);
    }
}

// ---------------------------------------------------------------------------
// Kernel 6: normalize + affine + residual.
// ---------------------------------------------------------------------------
__global__ __launch_bounds__(256) void final_kernel(
    const float* __restrict__ Zg, const float* __restrict__ xg,
    const float* __restrict__ stats, const float* __restrict__ gnw,
    const float* __restrict__ gnb, float* __restrict__ out)
{
    const size_t i4  = (size_t)blockIdx.x * 256 + threadIdx.x;  // float4 index
    const size_t idx = i4 * 4;
    const int bc = (int)(i4 / (HW_ / 4));   // b*128 + c
    const int c  = bc & 127;
    const int b  = bc >> 7;
    const int g  = c >> 2;
    const float mean = stats[((size_t)b * GROUPS_ + g) * 2 + 0];
    const float rstd = stats[((size_t)b * GROUPS_ + g) * 2 + 1];
    const float sc = rstd * gnw[c];
    const float sh = gnb[c] - mean * sc;
    const float4 z  = *(const float4*)(Zg + idx);
    const float4 xv = *(const float4*)(xg + idx);
    float4 o;
    o.x = z.x * sc + sh + xv.x;
    o.y = z.y * sc + sh + xv.y;
    o.z = z.z * sc + sh + xv.z;
    o.w = z.w * sc + sh + xv.w;
    *(float4*)(out + idx) = o;
}

// ---------------------------------------------------------------------------
extern "C" void kernel_launch(void* const* d_in, const int* in_sizes, int n_in,
                              void* d_out, int out_size, void* d_ws, size_t ws_size,
                              hipStream_t stream)
{
    const float* x       = (const float*)d_in[0];
    const float* w_theta = (const float*)d_in[1];
    const float* b_theta = (const float*)d_in[2];
    const float* w_phi   = (const float*)d_in[3];
    const float* b_phi   = (const float*)d_in[4];
    const float* w_g     = (const float*)d_in[5];
    const float* b_g     = (const float*)d_in[6];
    const float* w_W     = (const float*)d_in[7];
    const float* b_W     = (const float*)d_in[8];
    const float* gn_w    = (const float*)d_in[9];
    const float* gn_b    = (const float*)d_in[10];
    float* out = (float*)d_out;
    float* ws  = (float*)d_ws;

    // workspace layout (floats); peak use ~42.5 MB with aliasing
    float* Q    = ws;                             // [B][HW][64]   2,359,296
    float* Kb   = Q    + (size_t)B_ * HW_ * CI_;  // [B][NP][64]     589,824
    float* Vb   = Kb   + (size_t)B_ * NP_ * CI_;  //                 589,824
    float* phiF = Vb   + (size_t)B_ * NP_ * CI_;  // [B][HW][64]   2,359,296 (dead after pool)
    float* gF   = phiF + (size_t)B_ * HW_ * CI_;  // [B][HW][64]   2,359,296 (dead after pool)
    float* Y    = phiF;                           // reuse phiF region
    float* Z    = gF;                             // reuse gF region (+ 2,359,296 beyond it)
    float* stats = gF + (size_t)B_ * C_ * HW_;    // 256 floats

    proj_kernel <<<dim3(HW_ / 32, B_, 3), 256, 0, stream>>>(
        x, w_theta, b_theta, w_phi, b_phi, w_g, b_g, Q, phiF, gF);
    pool_kernel <<<dim3(NP_ * CI_ / 256, B_, 2), 256, 0, stream>>>(phiF, gF, Kb, Vb);
    attn_kernel <<<dim3(HW_ / 64, B_), 64, 0, stream>>>(Q, Kb, Vb, Y);
    conv2_kernel<<<dim3(HW_ / 64, B_), 256, 0, stream>>>(Y, w_W, b_W, Z);
    stats_kernel<<<dim3(GROUPS_, B_), 256, 0, stream>>>(Z, stats);
    final_kernel<<<dim3((B_ * C_ * HW_) / 1024, 1), 256, 0, stream>>>(
        Z, x, stats, gn_w, gn_b, out);
}

// Round 2
// 180.002 us; speedup vs baseline: 14.9390x; 14.9390x over previous
//
#include <hip/hip_runtime.h>
#include <math.h>

#define B_ 4
#define C_ 128
#define CI_ 64
#define H_ 96
#define W_ 96
#define HW_ (H_*W_)      // 9216
#define NP_ 2304         // 48*48
#define GROUPS_ 32
#define EPS_ 1e-5f

typedef __attribute__((ext_vector_type(8))) short bf16x8;
typedef __attribute__((ext_vector_type(4))) float f32x4;

__device__ inline f32x4 mfma16(bf16x8 a, bf16x8 b, f32x4 c) {
    return __builtin_amdgcn_mfma_f32_16x16x32_bf16(a, b, c, 0, 0, 0);
}

__device__ inline unsigned short f2bf(float x) {          // RNE f32->bf16
    unsigned u = __builtin_bit_cast(unsigned, x);
    return (unsigned short)((u + 0x7FFFu + ((u >> 16) & 1u)) >> 16);
}
__device__ inline float bf2f(unsigned short s) {
    return __builtin_bit_cast(float, (unsigned)s << 16);
}

// ---------------------------------------------------------------------------
// Kernel 1: fused 3-way 1x1 conv projections -> bf16 [b][n][ci]
// ---------------------------------------------------------------------------
__global__ __launch_bounds__(256) void proj_kernel(
    const float* __restrict__ x,
    const float* __restrict__ w_theta, const float* __restrict__ b_theta,
    const float* __restrict__ w_phi,   const float* __restrict__ b_phi,
    const float* __restrict__ w_g,     const float* __restrict__ b_g,
    unsigned short* __restrict__ Qo, unsigned short* __restrict__ phiF,
    unsigned short* __restrict__ gF)
{
    __shared__ float xs[C_ * 32];   // xs[c*32 + pix]
    __shared__ float ws[C_ * 68];   // ws[c*68 + ci]
    const int t    = threadIdx.x;
    const int tile = blockIdx.x;
    const int b    = blockIdx.y;
    const int mat  = blockIdx.z;
    const float* wsel = (mat == 0) ? w_theta : (mat == 1) ? w_phi : w_g;
    const float* bsel = (mat == 0) ? b_theta : (mat == 1) ? b_phi : b_g;
    unsigned short* osel = (mat == 0) ? Qo : (mat == 1) ? phiF : gF;
    const int n0 = tile * 32;

    {
        const int pix = t & 31;
        const int c0  = t >> 5;
        const float* xb = x + (size_t)b * C_ * HW_ + n0 + pix;
        for (int c = c0; c < C_; c += 8)
            xs[c * 32 + pix] = xb[(size_t)c * HW_];
    }
    for (int j = t; j < CI_ * C_; j += 256)
        ws[(j & 127) * 68 + (j >> 7)] = wsel[j];
    __syncthreads();

    const int tp = (t & 7) * 4;
    const int tc = (t >> 3) * 2;
    float acc[4][2] = {};
    #pragma unroll 4
    for (int c = 0; c < C_; ++c) {
        const float4 xv = *(const float4*)&xs[c * 32 + tp];
        const float2 wv = *(const float2*)&ws[c * 68 + tc];
        const float xa[4] = {xv.x, xv.y, xv.z, xv.w};
        #pragma unroll
        for (int i = 0; i < 4; ++i) {
            acc[i][0] += xa[i] * wv.x;
            acc[i][1] += xa[i] * wv.y;
        }
    }
    const float2 bb = *(const float2*)&bsel[tc];
    #pragma unroll
    for (int i = 0; i < 4; ++i) {
        unsigned pk = (unsigned)f2bf(acc[i][0] + bb.x)
                    | ((unsigned)f2bf(acc[i][1] + bb.y) << 16);
        *(unsigned*)&osel[((size_t)b * HW_ + n0 + tp + i) * CI_ + tc] = pk;
    }
}

// ---------------------------------------------------------------------------
// Kernel 2: 2x2 maxpool. K stays [b][m][ci]; V is TRANSPOSED to [b][ci][m].
// ---------------------------------------------------------------------------
__global__ __launch_bounds__(256) void pool_kernel(
    const unsigned short* __restrict__ phiF, const unsigned short* __restrict__ gF,
    unsigned short* __restrict__ Ko, unsigned short* __restrict__ Vt)
{
    const int t   = threadIdx.x;
    const int b   = blockIdx.y;
    const int mat = blockIdx.z;                 // 0 -> K, 1 -> V^T
    const int idx = blockIdx.x * 256 + t;       // 0..147455
    int m, ci;
    if (mat == 0) { m = idx >> 6; ci = idx & 63; }
    else          { ci = idx / NP_; m = idx - ci * NP_; }
    const int ph = m / 48, pw = m % 48;
    const int n00 = (ph * 2) * W_ + pw * 2;
    const unsigned short* src = mat ? gF : phiF;
    const unsigned short* p = src + ((size_t)b * HW_ + n00) * CI_ + ci;
    float v = fmaxf(fmaxf(bf2f(p[0]), bf2f(p[CI_])),
                    fmaxf(bf2f(p[(size_t)W_ * CI_]), bf2f(p[(size_t)(W_ + 1) * CI_])));
    unsigned short r = (unsigned short)(__builtin_bit_cast(unsigned, v) >> 16); // exact
    if (mat == 0) Ko[((size_t)b * NP_ + m) * CI_ + ci] = r;
    else          Vt[((size_t)b * CI_ + ci) * NP_ + m] = r;
}

// ---------------------------------------------------------------------------
// Kernel 3: bf16 MFMA flash attention.
// Block = 2 waves x 32 q-rows. KV tile = 64. Swapped QK^T (S^T = K*Q^T).
// K_lds[k][d], V_lds[d][k] both XOR-swizzled 128B rows.
// ---------------------------------------------------------------------------
__global__ __launch_bounds__(128) void attn_kernel(
    const unsigned short* __restrict__ Qg, const unsigned short* __restrict__ Kg,
    const unsigned short* __restrict__ Vt, float* __restrict__ Yg)
{
    __shared__ unsigned char Ks[64 * 128];       // 8 KB, swizzled
    __shared__ unsigned char Vs[64 * 128];       // 8 KB, swizzled ([d][k])
    __shared__ unsigned char Ps[2][32 * 144];    // per-wave P, 144B row stride

    const int t    = threadIdx.x;
    const int wv   = t >> 6;
    const int lane = t & 63;
    const int lr   = lane & 15;
    const int lg   = lane >> 4;
    const int b    = blockIdx.y;
    const int q0   = blockIdx.x * 64 + wv * 32;

    // Q fragments (kept in registers): qs in {0,1} sub-tiles, u in {0,1} k-steps
    bf16x8 qf[2][2];
    #pragma unroll
    for (int qs = 0; qs < 2; ++qs)
        #pragma unroll
        for (int u = 0; u < 2; ++u)
            qf[qs][u] = *(const bf16x8*)(Qg
                + ((size_t)b * HW_ + q0 + qs * 16 + lr) * CI_ + u * 32 + lg * 8);

    f32x4 o_acc[2][4];
    #pragma unroll
    for (int qs = 0; qs < 2; ++qs)
        #pragma unroll
        for (int dt = 0; dt < 4; ++dt)
            o_acc[qs][dt] = (f32x4){0.f, 0.f, 0.f, 0.f};
    float mrun[2] = {-1e30f, -1e30f};
    float lrun[2] = {0.f, 0.f};

    for (int kt = 0; kt < NP_ / 64; ++kt) {      // 36 KV tiles
        const int kv0 = kt * 64;
        __syncthreads();
        #pragma unroll
        for (int p = 0; p < 4; ++p) {            // stage K and V^T tiles
            const int idx = p * 128 + t;         // 0..511
            const int row = idx >> 3, ch = idx & 7;
            const int soff = row * 128 + ((ch * 16) ^ ((row & 7) << 4));
            *(float4*)&Ks[soff] =
                *(const float4*)(Kg + ((size_t)b * NP_ + kv0 + row) * CI_ + ch * 8);
            *(float4*)&Vs[soff] =
                *(const float4*)(Vt + ((size_t)b * CI_ + row) * NP_ + kv0 + ch * 8);
        }
        __syncthreads();

        #pragma unroll
        for (int qs = 0; qs < 2; ++qs) {
            // ---- S^T = K * Q^T : lane holds S[k = 16*kt4 + 4*lg + r][q = lr]
            f32x4 s[4];
            #pragma unroll
            for (int kt4 = 0; kt4 < 4; ++kt4) s[kt4] = (f32x4){0.f, 0.f, 0.f, 0.f};
            #pragma unroll
            for (int u = 0; u < 2; ++u)
                #pragma unroll
                for (int kt4 = 0; kt4 < 4; ++kt4) {
                    bf16x8 kf = *(const bf16x8*)&Ks[(kt4 * 16 + lr) * 128
                                   + ((64 * u + 16 * lg) ^ ((lr & 7) << 4))];
                    s[kt4] = mfma16(kf, qf[qs][u], s[kt4]);
                }

            // ---- online softmax (per q-row = lr; reduce over lg via shfl_xor)
            float tmax = -1e30f;
            #pragma unroll
            for (int kt4 = 0; kt4 < 4; ++kt4)
                #pragma unroll
                for (int r = 0; r < 4; ++r) tmax = fmaxf(tmax, s[kt4][r]);
            tmax = fmaxf(tmax, __shfl_xor(tmax, 16));
            tmax = fmaxf(tmax, __shfl_xor(tmax, 32));
            const float mnew = fmaxf(mrun[qs], tmax);

            float pv[16];
            float tsum = 0.f;
            #pragma unroll
            for (int kt4 = 0; kt4 < 4; ++kt4)
                #pragma unroll
                for (int r = 0; r < 4; ++r) {
                    const float e = __expf(s[kt4][r] - mnew);
                    pv[kt4 * 4 + r] = e;
                    tsum += e;
                }
            tsum += __shfl_xor(tsum, 16);
            tsum += __shfl_xor(tsum, 32);

            const float scale = __expf(mrun[qs] - mnew);
            lrun[qs] = lrun[qs] * scale + tsum;
            mrun[qs] = mnew;

            // rescale O (O-layout: lane holds rows q = 4*lg + r2, col = lr)
            #pragma unroll
            for (int r2 = 0; r2 < 4; ++r2) {
                const float sc = __shfl(scale, 4 * lg + r2);
                #pragma unroll
                for (int dt = 0; dt < 4; ++dt) o_acc[qs][dt][r2] *= sc;
            }

            // ---- P -> LDS (bf16, PV A-fragment layout [q][k], 144B stride)
            #pragma unroll
            for (int kt4 = 0; kt4 < 4; ++kt4) {
                const unsigned lo = (unsigned)f2bf(pv[kt4 * 4 + 0])
                                  | ((unsigned)f2bf(pv[kt4 * 4 + 1]) << 16);
                const unsigned hi = (unsigned)f2bf(pv[kt4 * 4 + 2])
                                  | ((unsigned)f2bf(pv[kt4 * 4 + 3]) << 16);
                const int base = lr * 144 + (16 * kt4 + 4 * lg) * 2;
                *(unsigned*)&Ps[wv][base]     = lo;
                *(unsigned*)&Ps[wv][base + 4] = hi;
            }

            // ---- O += P * V
            #pragma unroll
            for (int u = 0; u < 2; ++u) {
                bf16x8 pf = *(const bf16x8*)&Ps[wv][lr * 144 + 64 * u + 16 * lg];
                #pragma unroll
                for (int dt = 0; dt < 4; ++dt) {
                    bf16x8 vf = *(const bf16x8*)&Vs[(dt * 16 + lr) * 128
                                   + ((64 * u + 16 * lg) ^ ((lr & 7) << 4))];
                    o_acc[qs][dt] = mfma16(pf, vf, o_acc[qs][dt]);
                }
            }
        }
    }

    // ---- finalize: divide by l, store Y[b][n][ci] fp32
    #pragma unroll
    for (int qs = 0; qs < 2; ++qs)
        #pragma unroll
        for (int r2 = 0; r2 < 4; ++r2) {
            const float inv = 1.0f / __shfl(lrun[qs], 4 * lg + r2);
            const int q = q0 + qs * 16 + 4 * lg + r2;
            float* yp = Yg + ((size_t)b * HW_ + q) * CI_ + lr;
            #pragma unroll
            for (int dt = 0; dt < 4; ++dt)
                yp[dt * 16] = o_acc[qs][dt][r2] * inv;
        }
}

// ---------------------------------------------------------------------------
// Kernel 4: 1x1 conv back to 128 channels (fp32).
// ---------------------------------------------------------------------------
__global__ __launch_bounds__(256) void conv2_kernel(
    const float* __restrict__ Yg, const float* __restrict__ wW,
    const float* __restrict__ bW, float* __restrict__ Zg)
{
    __shared__ float ys[CI_ * 68];
    __shared__ float ws2[CI_ * 132];
    const int t  = threadIdx.x;
    const int b  = blockIdx.y;
    const int n0 = blockIdx.x * 64;

    const float* ybase = Yg + ((size_t)b * HW_ + n0) * CI_;
    for (int j = t; j < 64 * CI_; j += 256)
        ys[(j & 63) * 68 + (j >> 6)] = ybase[j];
    for (int j = t; j < C_ * CI_; j += 256)
        ws2[(j & 63) * 132 + (j >> 6)] = wW[j];
    __syncthreads();

    const int tp = (t & 15) * 4;
    const int to = (t >> 4) * 8;
    float acc[4][8] = {};
    #pragma unroll 2
    for (int ci = 0; ci < CI_; ++ci) {
        const float4 yv  = *(const float4*)&ys[ci * 68 + tp];
        const float4 wv0 = *(const float4*)&ws2[ci * 132 + to];
        const float4 wv1 = *(const float4*)&ws2[ci * 132 + to + 4];
        const float ya[4] = {yv.x, yv.y, yv.z, yv.w};
        const float wa[8] = {wv0.x, wv0.y, wv0.z, wv0.w, wv1.x, wv1.y, wv1.z, wv1.w};
        #pragma unroll
        for (int i = 0; i < 4; ++i)
            #pragma unroll
            for (int j = 0; j < 8; ++j)
                acc[i][j] += ya[i] * wa[j];
    }
    #pragma unroll
    for (int j = 0; j < 8; ++j) {
        const int o = to + j;
        const float bb = bW[o];
        float* zp = Zg + ((size_t)b * C_ + o) * HW_ + n0 + tp;
        float4 v = { acc[0][j] + bb, acc[1][j] + bb, acc[2][j] + bb, acc[3][j] + bb };
        *(float4*)zp = v;
    }
}

// ---------------------------------------------------------------------------
// Kernel 5: GroupNorm stats (deterministic).
// ---------------------------------------------------------------------------
__global__ __launch_bounds__(256) void stats_kernel(
    const float* __restrict__ Zg, float* __restrict__ stats)
{
    const int t  = threadIdx.x;
    const int gr = blockIdx.x;
    const int b  = blockIdx.y;
    const float4* zp = (const float4*)(Zg + ((size_t)b * C_ + gr * 4) * HW_);
    float s = 0.f, ss = 0.f;
    for (int i = t; i < HW_; i += 256) {
        const float4 v = zp[i];
        s  += v.x + v.y + v.z + v.w;
        ss += v.x*v.x + v.y*v.y + v.z*v.z + v.w*v.w;
    }
    __shared__ float rs[256], rq[256];
    rs[t] = s; rq[t] = ss;
    __syncthreads();
    for (int off = 128; off > 0; off >>= 1) {
        if (t < off) { rs[t] += rs[t + off]; rq[t] += rq[t + off]; }
        __syncthreads();
    }
    if (t == 0) {
        const float invn = 1.0f / (4 * HW_);
        const float mean = rs[0] * invn;
        const float var  = rq[0] * invn - mean * mean;
        stats[((size_t)b * GROUPS_ + gr) * 2 + 0] = mean;
        stats[((size_t)b * GROUPS_ + gr) * 2 + 1] = rsqrtf(var + EPS_);
    }
}

// ---------------------------------------------------------------------------
// Kernel 6: normalize + affine + residual.
// ---------------------------------------------------------------------------
__global__ __launch_bounds__(256) void final_kernel(
    const float* __restrict__ Zg, const float* __restrict__ xg,
    const float* __restrict__ stats, const float* __restrict__ gnw,
    const float* __restrict__ gnb, float* __restrict__ out)
{
    const size_t i4  = (size_t)blockIdx.x * 256 + threadIdx.x;
    const size_t idx = i4 * 4;
    const int bc = (int)(i4 / (HW_ / 4));
    const int c  = bc & 127;
    const int b  = bc >> 7;
    const int g  = c >> 2;
    const float mean = stats[((size_t)b * GROUPS_ + g) * 2 + 0];
    const float rstd = stats[((size_t)b * GROUPS_ + g) * 2 + 1];
    const float sc = rstd * gnw[c];
    const float sh = gnb[c] - mean * sc;
    const float4 z  = *(const float4*)(Zg + idx);
    const float4 xv = *(const float4*)(xg + idx);
    float4 o;
    o.x = z.x * sc + sh + xv.x;
    o.y = z.y * sc + sh + xv.y;
    o.z = z.z * sc + sh + xv.z;
    o.w = z.w * sc + sh + xv.w;
    *(float4*)(out + idx) = o;
}

// ---------------------------------------------------------------------------
extern "C" void kernel_launch(void* const* d_in, const int* in_sizes, int n_in,
                              void* d_out, int out_size, void* d_ws, size_t ws_size,
                              hipStream_t stream)
{
    const float* x       = (const float*)d_in[0];
    const float* w_theta = (const float*)d_in[1];
    const float* b_theta = (const float*)d_in[2];
    const float* w_phi   = (const float*)d_in[3];
    const float* b_phi   = (const float*)d_in[4];
    const float* w_g     = (const float*)d_in[5];
    const float* b_g     = (const float*)d_in[6];
    const float* w_W     = (const float*)d_in[7];
    const float* b_W     = (const float*)d_in[8];
    const float* gn_w    = (const float*)d_in[9];
    const float* gn_b    = (const float*)d_in[10];
    float* out = (float*)d_out;
    char* wsb  = (char*)d_ws;

    // workspace layout (bytes)
    unsigned short* Q    = (unsigned short*)(wsb);             //  4,718,592
    unsigned short* K    = (unsigned short*)(wsb +  4718592);  //  1,179,648
    unsigned short* Vt   = (unsigned short*)(wsb +  5898240);  //  1,179,648
    unsigned short* phiF = (unsigned short*)(wsb +  7077888);  //  4,718,592
    unsigned short* gF   = (unsigned short*)(wsb + 11796480);  //  4,718,592
    float* Y             = (float*)(wsb +  7077888);           //  9,437,184 (aliases phiF+gF, dead after pool)
    float* Z             = (float*)(wsb + 16515072);           // 18,874,368
    float* stats         = (float*)(wsb + 35389440);           //  1 KB

    proj_kernel <<<dim3(HW_ / 32, B_, 3), 256, 0, stream>>>(
        x, w_theta, b_theta, w_phi, b_phi, w_g, b_g, Q, phiF, gF);
    pool_kernel <<<dim3(NP_ * CI_ / 256, B_, 2), 256, 0, stream>>>(phiF, gF, K, Vt);
    attn_kernel <<<dim3(HW_ / 64, B_), 128, 0, stream>>>(Q, K, Vt, Y);
    conv2_kernel<<<dim3(HW_ / 64, B_), 256, 0, stream>>>(Y, w_W, b_W, Z);
    stats_kernel<<<dim3(GROUPS_, B_), 256, 0, stream>>>(Z, stats);
    final_kernel<<<dim3((B_ * C_ * HW_) / 1024, 1), 256, 0, stream>>>(
        Z, x, stats, gn_w, gn_b, out);
}